// Round 9
// baseline (1013.562 us; speedup 1.0000x reference)
//
#include <hip/hip_runtime.h>
#include <math.h>

// Problem constants (from reference)
#define N_Q 4096
#define M_K 8192
#define D_DIM 512
#define P_IDX 4
#define INV_TEMP 10.0f

#define NCHUNK 128          // 8192 / 64-col chunks

typedef __attribute__((ext_vector_type(4))) _Float16 f16x4;
typedef __attribute__((ext_vector_type(8))) _Float16 f16x8;
typedef __attribute__((ext_vector_type(16))) float f32x16;

// ---------------------------------------------------------------------------
// Convert fp32 -> fp16 (RN), Q and K fused in one launch.
// ---------------------------------------------------------------------------
__global__ __launch_bounds__(256)
void conv_f16(const float* __restrict__ Q, const float* __restrict__ K,
              _Float16* __restrict__ h, int nq4, int ntot4)
{
    int i = blockIdx.x * 256 + threadIdx.x;
    if (i >= ntot4) return;
    float4 v = (i < nq4) ? ((const float4*)Q)[i] : ((const float4*)K)[i - nq4];
    f16x4 o;
    o.x = (_Float16)v.x; o.y = (_Float16)v.y;
    o.z = (_Float16)v.z; o.w = (_Float16)v.w;
    ((f16x4*)h)[i] = o;
}

__device__ __forceinline__ void gload16(const void* g, const void* l) {
    __builtin_amdgcn_global_load_lds(
        (const __attribute__((address_space(1))) unsigned int*)g,
        (__attribute__((address_space(3))) unsigned int*)l, 16, 0, 0);
}

// ---------------------------------------------------------------------------
// Single-pass fp16 MFMA GEMM: 128x128 tile, BK=32, 4 waves (2x2),
// 32x32x16_f16 MFMA, single 16 KB staging buffer, 2-barrier K-loop (16
// iters).  18 KB LDS + 64 VGPR -> 8 blocks/CU = 32 waves (100% occupancy);
// latency hidden by TLP.  Fused scale/ignore-mask/per-64col-chunk
// {max,sumexp,argmax} epilogue with u64-key argmax reduce.
// Grid (32, 64) natural order, block 256.
// ---------------------------------------------------------------------------
__global__ __launch_bounds__(256, 8)
void scores_mfma(const _Float16* __restrict__ Qh, const _Float16* __restrict__ Kh,
                 const int* __restrict__ ign, float4* __restrict__ part)
{
    // plane layout: [oct(k/8, 0..3)][row(128)][8 f16] = 4096 halves (8 KB).
    // plane 0 = Q, plane 1 = K.  Total 16 KB + 2 KB ign.
    __shared__ __align__(16) _Float16 smem[2 * 4096];
    __shared__ int ign_s[128][P_IDX];

    const int tid = threadIdx.x;          // 0..255
    const int lane = tid & 63;
    const int wave = tid >> 6;            // 0..3
    const int wr = wave >> 1, wc = wave & 1;
    const int hi = lane >> 5, lx = lane & 31;
    const int row0 = blockIdx.x * 128;
    const int col0 = blockIdx.y * 128;
    const int by = blockIdx.y;

    {   // stage ignore indices (512 ints, 2 per thread)
        int i0 = tid * 2;
        ign_s[i0 >> 2][i0 & 3] = ign[(size_t)(row0 + (i0 >> 2)) * P_IDX + (i0 & 3)];
        int i1 = i0 + 1;
        ign_s[i1 >> 2][i1 & 3] = ign[(size_t)(row0 + (i1 >> 2)) * P_IDX + (i1 & 3)];
    }

    // 4 staging streams per thread: 2 chunks per plane (512 chunks/plane)
    const _Float16* srcs[4];
    int dsts[4];
#pragma unroll
    for (int it = 0; it < 4; ++it) {
        const int plane = it >> 1;
        const int c = (it & 1) * 256 + tid;       // chunk 0..511 within plane
        const int oct = c >> 7, r = c & 127;
        const _Float16* base = (plane == 0) ? Qh : Kh;
        const int grow = ((plane == 0) ? row0 : col0) + r;
        srcs[it] = base + (size_t)grow * D_DIM + oct * 8;
        dsts[it] = plane * 4096 + c * 8;
    }

    f32x16 acc[2][2];
#pragma unroll
    for (int i = 0; i < 2; ++i)
#pragma unroll
        for (int j = 0; j < 2; ++j) acc[i][j] = (f32x16)0.f;

    for (int t = 0; t < 16; ++t) {
        const int k0 = t * 32;
        // stage K-tile t (4 x 16B per thread, async global->LDS)
#pragma unroll
        for (int it = 0; it < 4; ++it)
            gload16(srcs[it] + k0, &smem[dsts[it]]);
        __syncthreads();    // drains each wave's vmcnt -> tile fully staged

        f16x8 a[2][2], b[2][2];
#pragma unroll
        for (int ks = 0; ks < 2; ++ks) {
            const int oct = ks * 2 + hi;
#pragma unroll
            for (int i = 0; i < 2; ++i) {
                const int oa = (oct * 128 + wr * 64 + i * 32 + lx) * 8;
                a[i][ks] = *(const f16x8*)&smem[oa];               // Q plane
            }
#pragma unroll
            for (int j = 0; j < 2; ++j) {
                const int ob = (oct * 128 + wc * 64 + j * 32 + lx) * 8;
                b[j][ks] = *(const f16x8*)&smem[4096 + ob];        // K plane
            }
        }
#pragma unroll
        for (int ks = 0; ks < 2; ++ks)
#pragma unroll
            for (int i = 0; i < 2; ++i)
#pragma unroll
                for (int j = 0; j < 2; ++j)
                    acc[i][j] = __builtin_amdgcn_mfma_f32_32x32x16_f16(a[i][ks], b[j][ks], acc[i][j], 0, 0, 0);
        __syncthreads();    // all waves done reading before next stage
    }

    // Epilogue: C row = row0 + wr*64 + i*32 + (r&3)+8*(r>>2)+4*hi,
    //           col = col0 + wc*64 + j*32 + lx.  Chunk (64 cols) = by*2 + wc.
    // argmax via sortable u64 key: [monotone(float) : 32][~col : 32];
    // first-occurrence tie-break preserved (larger ~col == smaller col).
    const int chunk = by * 2 + wc;
#pragma unroll
    for (int i = 0; i < 2; ++i) {
#pragma unroll
        for (int r = 0; r < 16; ++r) {
            const int rl = wr * 64 + i * 32 + (r & 3) + 8 * (r >> 2) + 4 * hi;
            const int ig0 = ign_s[rl][0], ig1 = ign_s[rl][1];
            const int ig2 = ign_s[rl][2], ig3 = ign_s[rl][3];
            const int c0 = col0 + wc * 64 + lx;
            const int c1 = c0 + 32;
            float x0 = acc[i][0][r] * INV_TEMP;
            float x1 = acc[i][1][r] * INV_TEMP;
            if (c0 == ig0 || c0 == ig1 || c0 == ig2 || c0 == ig3) x0 = -INFINITY;
            if (c1 == ig0 || c1 == ig1 || c1 == ig2 || c1 == ig3) x1 = -INFINITY;
            unsigned u0 = __float_as_uint(x0);
            u0 ^= (unsigned)(((int)u0 >> 31)) | 0x80000000u;
            unsigned u1 = __float_as_uint(x1);
            u1 ^= (unsigned)(((int)u1 >> 31)) | 0x80000000u;
            unsigned long long k0 =
                ((unsigned long long)u0 << 32) | (0xFFFFFFFFu - (unsigned)c0);
            unsigned long long k1 =
                ((unsigned long long)u1 << 32) | (0xFFFFFFFFu - (unsigned)c1);
            unsigned long long km = (k0 >= k1) ? k0 : k1;
#pragma unroll
            for (int off = 16; off >= 1; off >>= 1) {
                unsigned long long ko = __shfl_xor(km, off);
                if (ko > km) km = ko;
            }
            // decode winning value + column
            unsigned um = (unsigned)(km >> 32);
            unsigned ub = (um & 0x80000000u) ? (um ^ 0x80000000u) : ~um;
            float bm = __uint_as_float(ub);
            int bi = (int)(0xFFFFFFFFu - (unsigned)km);
            float se = __expf(x0 - bm) + __expf(x1 - bm);  // exp(-inf)=0
#pragma unroll
            for (int off = 16; off >= 1; off >>= 1) se += __shfl_xor(se, off);
            if (lx == 0)
                part[(size_t)(row0 + rl) * NCHUNK + chunk] =
                    make_float4(bm, se, __int_as_float(bi), 0.f);
        }
    }
}

// ---------------------------------------------------------------------------
// Kernel B: one wave per row.  Merge 128 chunk partials -> lse + argmax;
// positives recomputed EXACTLY in fp32 (with duplicate dedup) -> logp is
// immune to fp16 GEMM noise except through lse.
// ---------------------------------------------------------------------------
__global__ __launch_bounds__(64)
void combine_kernel(const float4* __restrict__ part,
                    const float* __restrict__ Q, const float* __restrict__ K,
                    const int* __restrict__ pos,
                    float* __restrict__ logp, float* __restrict__ corrects)
{
    const int row = blockIdx.x;
    const int lane = threadIdx.x;

    float4 p0 = part[(size_t)row * NCHUNK + lane];
    float4 p1 = part[(size_t)row * NCHUNK + 64 + lane];
    float m, s, av; int ai;
    if (p0.x >= p1.x) { av = p0.x; ai = __float_as_int(p0.z); }
    else              { av = p1.x; ai = __float_as_int(p1.z); }
    m = fmaxf(p0.x, p1.x);
    s = p0.y * expf(p0.x - m) + p1.y * expf(p1.x - m);

#pragma unroll
    for (int off = 32; off >= 1; off >>= 1) {
        float om = __shfl_xor(m, off);
        float os = __shfl_xor(s, off);
        float oav = __shfl_xor(av, off);
        int oi = __shfl_xor(ai, off);
        float nm = fmaxf(m, om);
        s = s * expf(m - nm) + os * expf(om - nm);
        m = nm;
        if (oav > av || (oav == av && oi < ai)) { av = oav; ai = oi; }
    }
    float lse = m + logf(s);

    int pi[4];
#pragma unroll
    for (int p = 0; p < 4; ++p) pi[p] = pos[row * P_IDX + p];

    // positive dot-products in exact fp32: lane covers 8 consecutive d-elements
    const float4* q4 = (const float4*)(Q + (size_t)row * D_DIM);
    float4 qa = q4[lane * 2], qb = q4[lane * 2 + 1];
    float d[4];
#pragma unroll
    for (int p = 0; p < 4; ++p) {
        const float4* k4 = (const float4*)(K + (size_t)pi[p] * D_DIM);
        float4 ka = k4[lane * 2], kb = k4[lane * 2 + 1];
        d[p] = qa.x * ka.x + qa.y * ka.y + qa.z * ka.z + qa.w * ka.w
             + qb.x * kb.x + qb.y * kb.y + qb.z * kb.z + qb.w * kb.w;
    }
#pragma unroll
    for (int off = 32; off >= 1; off >>= 1) {
#pragma unroll
        for (int p = 0; p < 4; ++p) d[p] += __shfl_xor(d[p], off);
    }

    if (lane == 0) {
        float ps[4];
#pragma unroll
        for (int p = 0; p < 4; ++p) ps[p] = d[p] * INV_TEMP;
        const bool v1 = (pi[1] != pi[0]);
        const bool v2 = (pi[2] != pi[0]) && (pi[2] != pi[1]);
        const bool v3 = (pi[3] != pi[0]) && (pi[3] != pi[1]) && (pi[3] != pi[2]);
        float pm = ps[0];
        if (v1) pm = fmaxf(pm, ps[1]);
        if (v2) pm = fmaxf(pm, ps[2]);
        if (v3) pm = fmaxf(pm, ps[3]);
        float pse = expf(ps[0] - pm);
        if (v1) pse += expf(ps[1] - pm);
        if (v2) pse += expf(ps[2] - pm);
        if (v3) pse += expf(ps[3] - pm);
        float pos_lse = pm + logf(pse);
        logp[row] = pos_lse - lse;
        bool corr = (ai == pi[0]) || (ai == pi[1]) || (ai == pi[2]) || (ai == pi[3]);
        corrects[row] = corr ? 1.0f : 0.0f;
    }
}

// ---------------------------------------------------------------------------
// Kernel C: deterministic fixed-order reduction of logp -> loss
// ---------------------------------------------------------------------------
__global__ __launch_bounds__(256)
void loss_kernel(const float* __restrict__ logp, float* __restrict__ out)
{
    __shared__ float sm[256];
    const int t = threadIdx.x;
    float s = 0.f;
    for (int i = t; i < N_Q; i += 256) s += logp[i];
    sm[t] = s;
    __syncthreads();
    for (int off = 128; off >= 1; off >>= 1) {
        if (t < off) sm[t] += sm[t + off];
        __syncthreads();
    }
    if (t == 0) out[0] = -sm[0];
}

// ---------------------------------------------------------------------------
extern "C" void kernel_launch(void* const* d_in, const int* in_sizes, int n_in,
                              void* d_out, int out_size, void* d_ws, size_t ws_size,
                              hipStream_t stream)
{
    const float* Q = (const float*)d_in[0];
    const float* K = (const float*)d_in[1];
    const int* pos = (const int*)d_in[2];
    const int* ign = (const int*)d_in[3];
    float* out = (float*)d_out;

    // workspace layout (total ~20 MB)
    _Float16* Qh = (_Float16*)d_ws;                              // 4 MB
    _Float16* Kh = Qh + (size_t)N_Q * D_DIM;                     // 8 MB (contiguous after Qh)
    float4* part = (float4*)(Kh + (size_t)M_K * D_DIM);          // 8 MB
    float* logp = (float*)(part + (size_t)N_Q * NCHUNK);         // 16 KB

    const int nq4 = N_Q * D_DIM / 4;
    const int ntot4 = (N_Q + M_K) * D_DIM / 4;
    conv_f16<<<(ntot4 + 255) / 256, 256, 0, stream>>>(Q, K, Qh, nq4, ntot4);

    dim3 gridA(N_Q / 128, M_K / 128);   // 32 x 64, natural order
    scores_mfma<<<gridA, 256, 0, stream>>>(Qh, Kh, ign, part);
    combine_kernel<<<N_Q, 64, 0, stream>>>(part, Q, K, pos, logp, out + 1);
    loss_kernel<<<1, 256, 0, stream>>>(logp, out);
}

// Round 10
// 121.898 us; speedup vs baseline: 8.3148x; 8.3148x over previous
//
#include <hip/hip_runtime.h>
#include <math.h>

// Problem constants (from reference)
#define N_Q 4096
#define M_K 8192
#define D_DIM 512
#define P_IDX 4
#define INV_TEMP 10.0f

#define NCHUNK 128          // 8192 / 64-col chunks

typedef __attribute__((ext_vector_type(4))) _Float16 f16x4;
typedef __attribute__((ext_vector_type(8))) _Float16 f16x8;
typedef __attribute__((ext_vector_type(16))) float f32x16;

// ---------------------------------------------------------------------------
// Convert fp32 -> fp16 (RN), Q and K fused in one launch.
// ---------------------------------------------------------------------------
__global__ __launch_bounds__(256)
void conv_f16(const float* __restrict__ Q, const float* __restrict__ K,
              _Float16* __restrict__ h, int nq4, int ntot4)
{
    int i = blockIdx.x * 256 + threadIdx.x;
    if (i >= ntot4) return;
    float4 v = (i < nq4) ? ((const float4*)Q)[i] : ((const float4*)K)[i - nq4];
    f16x4 o;
    o.x = (_Float16)v.x; o.y = (_Float16)v.y;
    o.z = (_Float16)v.z; o.w = (_Float16)v.w;
    ((f16x4*)h)[i] = o;
}

__device__ __forceinline__ void gload16(const void* g, const void* l) {
    __builtin_amdgcn_global_load_lds(
        (const __attribute__((address_space(1))) unsigned int*)g,
        (__attribute__((address_space(3))) unsigned int*)l, 16, 0, 0);
}

// ---------------------------------------------------------------------------
// Single-pass fp16 MFMA GEMM: 128x128 tile, BK=32, 4 waves (2x2),
// 32x32x16_f16 MFMA, DOUBLE-buffered 2x16 KB staging, ONE barrier per
// K-step (stage t+1 issued before compute t -> latency hidden under MFMA).
// 34 KB LDS + <=128 VGPR -> 4 blocks/CU co-resident (16 waves TLP).
// Fused scale/ignore-mask/per-64col-chunk {max,sumexp,argmax} epilogue
// with u64-key argmax reduce.  Grid (32, 64) natural order, block 256.
// ---------------------------------------------------------------------------
__global__ __launch_bounds__(256, 4)
void scores_mfma(const _Float16* __restrict__ Qh, const _Float16* __restrict__ Kh,
                 const int* __restrict__ ign, float4* __restrict__ part)
{
    // buffer layout: [oct(k/8, 0..3)][row(128)][8 f16]; plane0=Q, plane1=K.
    // 8 KB per plane, 16 KB per buffer, 2 buffers.
    __shared__ __align__(16) _Float16 smem[2][2 * 4096];
    __shared__ int ign_s[128][P_IDX];

    const int tid = threadIdx.x;          // 0..255
    const int lane = tid & 63;
    const int wave = tid >> 6;            // 0..3
    const int wr = wave >> 1, wc = wave & 1;
    const int hi = lane >> 5, lx = lane & 31;
    const int row0 = blockIdx.x * 128;
    const int col0 = blockIdx.y * 128;
    const int by = blockIdx.y;

    {   // stage ignore indices (512 ints, 2 per thread)
        int i0 = tid * 2;
        ign_s[i0 >> 2][i0 & 3] = ign[(size_t)(row0 + (i0 >> 2)) * P_IDX + (i0 & 3)];
        int i1 = i0 + 1;
        ign_s[i1 >> 2][i1 & 3] = ign[(size_t)(row0 + (i1 >> 2)) * P_IDX + (i1 & 3)];
    }

    // 4 staging streams per thread: 2 chunks per plane (512 chunks/plane)
    const _Float16* srcs[4];
    int dsts[4];
#pragma unroll
    for (int it = 0; it < 4; ++it) {
        const int plane = it >> 1;
        const int c = (it & 1) * 256 + tid;       // chunk 0..511 within plane
        const int oct = c >> 7, r = c & 127;
        const _Float16* base = (plane == 0) ? Qh : Kh;
        const int grow = ((plane == 0) ? row0 : col0) + r;
        srcs[it] = base + (size_t)grow * D_DIM + oct * 8;
        dsts[it] = plane * 4096 + c * 8;
    }

    f32x16 acc[2][2];
#pragma unroll
    for (int i = 0; i < 2; ++i)
#pragma unroll
        for (int j = 0; j < 2; ++j) acc[i][j] = (f32x16)0.f;

    // prologue: stage K-tile 0 into buffer 0
#pragma unroll
    for (int it = 0; it < 4; ++it)
        gload16(srcs[it], &smem[0][dsts[it]]);
    __syncthreads();        // buf0 fully staged (drains vmcnt, all waves)

    for (int t = 0; t < 16; ++t) {
        const int cur = t & 1;
        // issue prefetch of tile t+1 FIRST -> its L2 latency hides under
        // this iteration's ds_read+MFMA work
        if (t < 15) {
            const int k0 = (t + 1) * 32;
#pragma unroll
            for (int it = 0; it < 4; ++it)
                gload16(srcs[it] + k0, &smem[cur ^ 1][dsts[it]]);
        }

        const _Float16* sbuf = smem[cur];
        f16x8 a[2][2], b[2][2];
#pragma unroll
        for (int ks = 0; ks < 2; ++ks) {
            const int oct = ks * 2 + hi;
#pragma unroll
            for (int i = 0; i < 2; ++i) {
                const int oa = (oct * 128 + wr * 64 + i * 32 + lx) * 8;
                a[i][ks] = *(const f16x8*)&sbuf[oa];               // Q plane
            }
#pragma unroll
            for (int j = 0; j < 2; ++j) {
                const int ob = (oct * 128 + wc * 64 + j * 32 + lx) * 8;
                b[j][ks] = *(const f16x8*)&sbuf[4096 + ob];        // K plane
            }
        }
#pragma unroll
        for (int ks = 0; ks < 2; ++ks)
#pragma unroll
            for (int i = 0; i < 2; ++i)
#pragma unroll
                for (int j = 0; j < 2; ++j)
                    acc[i][j] = __builtin_amdgcn_mfma_f32_32x32x16_f16(a[i][ks], b[j][ks], acc[i][j], 0, 0, 0);

        // one barrier per K-step: drains my prefetch (mostly landed already),
        // and guarantees (a) everyone done reading buf[cur] before t+1
        // overwrites it, (b) buf[cur^1] fully staged for next iteration.
        __syncthreads();
    }

    // Epilogue: C row = row0 + wr*64 + i*32 + (r&3)+8*(r>>2)+4*hi,
    //           col = col0 + wc*64 + j*32 + lx.  Chunk (64 cols) = by*2 + wc.
    // argmax via sortable u64 key: [monotone(float) : 32][~col : 32];
    // first-occurrence tie-break preserved (larger ~col == smaller col).
    const int chunk = by * 2 + wc;
#pragma unroll
    for (int i = 0; i < 2; ++i) {
#pragma unroll
        for (int r = 0; r < 16; ++r) {
            const int rl = wr * 64 + i * 32 + (r & 3) + 8 * (r >> 2) + 4 * hi;
            const int ig0 = ign_s[rl][0], ig1 = ign_s[rl][1];
            const int ig2 = ign_s[rl][2], ig3 = ign_s[rl][3];
            const int c0 = col0 + wc * 64 + lx;
            const int c1 = c0 + 32;
            float x0 = acc[i][0][r] * INV_TEMP;
            float x1 = acc[i][1][r] * INV_TEMP;
            if (c0 == ig0 || c0 == ig1 || c0 == ig2 || c0 == ig3) x0 = -INFINITY;
            if (c1 == ig0 || c1 == ig1 || c1 == ig2 || c1 == ig3) x1 = -INFINITY;
            unsigned u0 = __float_as_uint(x0);
            u0 ^= (unsigned)(((int)u0 >> 31)) | 0x80000000u;
            unsigned u1 = __float_as_uint(x1);
            u1 ^= (unsigned)(((int)u1 >> 31)) | 0x80000000u;
            unsigned long long k0 =
                ((unsigned long long)u0 << 32) | (0xFFFFFFFFu - (unsigned)c0);
            unsigned long long k1 =
                ((unsigned long long)u1 << 32) | (0xFFFFFFFFu - (unsigned)c1);
            unsigned long long km = (k0 >= k1) ? k0 : k1;
#pragma unroll
            for (int off = 16; off >= 1; off >>= 1) {
                unsigned long long ko = __shfl_xor(km, off);
                if (ko > km) km = ko;
            }
            // decode winning value + column
            unsigned um = (unsigned)(km >> 32);
            unsigned ub = (um & 0x80000000u) ? (um ^ 0x80000000u) : ~um;
            float bm = __uint_as_float(ub);
            int bi = (int)(0xFFFFFFFFu - (unsigned)km);
            float se = __expf(x0 - bm) + __expf(x1 - bm);  // exp(-inf)=0
#pragma unroll
            for (int off = 16; off >= 1; off >>= 1) se += __shfl_xor(se, off);
            if (lx == 0)
                part[(size_t)(row0 + rl) * NCHUNK + chunk] =
                    make_float4(bm, se, __int_as_float(bi), 0.f);
        }
    }
}

// ---------------------------------------------------------------------------
// Kernel B: one wave per row.  Merge 128 chunk partials -> lse + argmax;
// positives recomputed EXACTLY in fp32 (with duplicate dedup) -> logp is
// immune to fp16 GEMM noise except through lse.
// ---------------------------------------------------------------------------
__global__ __launch_bounds__(64)
void combine_kernel(const float4* __restrict__ part,
                    const float* __restrict__ Q, const float* __restrict__ K,
                    const int* __restrict__ pos,
                    float* __restrict__ logp, float* __restrict__ corrects)
{
    const int row = blockIdx.x;
    const int lane = threadIdx.x;

    float4 p0 = part[(size_t)row * NCHUNK + lane];
    float4 p1 = part[(size_t)row * NCHUNK + 64 + lane];
    float m, s, av; int ai;
    if (p0.x >= p1.x) { av = p0.x; ai = __float_as_int(p0.z); }
    else              { av = p1.x; ai = __float_as_int(p1.z); }
    m = fmaxf(p0.x, p1.x);
    s = p0.y * expf(p0.x - m) + p1.y * expf(p1.x - m);

#pragma unroll
    for (int off = 32; off >= 1; off >>= 1) {
        float om = __shfl_xor(m, off);
        float os = __shfl_xor(s, off);
        float oav = __shfl_xor(av, off);
        int oi = __shfl_xor(ai, off);
        float nm = fmaxf(m, om);
        s = s * expf(m - nm) + os * expf(om - nm);
        m = nm;
        if (oav > av || (oav == av && oi < ai)) { av = oav; ai = oi; }
    }
    float lse = m + logf(s);

    int pi[4];
#pragma unroll
    for (int p = 0; p < 4; ++p) pi[p] = pos[row * P_IDX + p];

    // positive dot-products in exact fp32: lane covers 8 consecutive d-elements
    const float4* q4 = (const float4*)(Q + (size_t)row * D_DIM);
    float4 qa = q4[lane * 2], qb = q4[lane * 2 + 1];
    float d[4];
#pragma unroll
    for (int p = 0; p < 4; ++p) {
        const float4* k4 = (const float4*)(K + (size_t)pi[p] * D_DIM);
        float4 ka = k4[lane * 2], kb = k4[lane * 2 + 1];
        d[p] = qa.x * ka.x + qa.y * ka.y + qa.z * ka.z + qa.w * ka.w
             + qb.x * kb.x + qb.y * kb.y + qb.z * kb.z + qb.w * kb.w;
    }
#pragma unroll
    for (int off = 32; off >= 1; off >>= 1) {
#pragma unroll
        for (int p = 0; p < 4; ++p) d[p] += __shfl_xor(d[p], off);
    }

    if (lane == 0) {
        float ps[4];
#pragma unroll
        for (int p = 0; p < 4; ++p) ps[p] = d[p] * INV_TEMP;
        const bool v1 = (pi[1] != pi[0]);
        const bool v2 = (pi[2] != pi[0]) && (pi[2] != pi[1]);
        const bool v3 = (pi[3] != pi[0]) && (pi[3] != pi[1]) && (pi[3] != pi[2]);
        float pm = ps[0];
        if (v1) pm = fmaxf(pm, ps[1]);
        if (v2) pm = fmaxf(pm, ps[2]);
        if (v3) pm = fmaxf(pm, ps[3]);
        float pse = expf(ps[0] - pm);
        if (v1) pse += expf(ps[1] - pm);
        if (v2) pse += expf(ps[2] - pm);
        if (v3) pse += expf(ps[3] - pm);
        float pos_lse = pm + logf(pse);
        logp[row] = pos_lse - lse;
        bool corr = (ai == pi[0]) || (ai == pi[1]) || (ai == pi[2]) || (ai == pi[3]);
        corrects[row] = corr ? 1.0f : 0.0f;
    }
}

// ---------------------------------------------------------------------------
// Kernel C: deterministic fixed-order reduction of logp -> loss
// ---------------------------------------------------------------------------
__global__ __launch_bounds__(256)
void loss_kernel(const float* __restrict__ logp, float* __restrict__ out)
{
    __shared__ float sm[256];
    const int t = threadIdx.x;
    float s = 0.f;
    for (int i = t; i < N_Q; i += 256) s += logp[i];
    sm[t] = s;
    __syncthreads();
    for (int off = 128; off >= 1; off >>= 1) {
        if (t < off) sm[t] += sm[t + off];
        __syncthreads();
    }
    if (t == 0) out[0] = -sm[0];
}

// ---------------------------------------------------------------------------
extern "C" void kernel_launch(void* const* d_in, const int* in_sizes, int n_in,
                              void* d_out, int out_size, void* d_ws, size_t ws_size,
                              hipStream_t stream)
{
    const float* Q = (const float*)d_in[0];
    const float* K = (const float*)d_in[1];
    const int* pos = (const int*)d_in[2];
    const int* ign = (const int*)d_in[3];
    float* out = (float*)d_out;

    // workspace layout (total ~20 MB)
    _Float16* Qh = (_Float16*)d_ws;                              // 4 MB
    _Float16* Kh = Qh + (size_t)N_Q * D_DIM;                     // 8 MB (contiguous after Qh)
    float4* part = (float4*)(Kh + (size_t)M_K * D_DIM);          // 8 MB
    float* logp = (float*)(part + (size_t)N_Q * NCHUNK);         // 16 KB

    const int nq4 = N_Q * D_DIM / 4;
    const int ntot4 = (N_Q + M_K) * D_DIM / 4;
    conv_f16<<<(ntot4 + 255) / 256, 256, 0, stream>>>(Q, K, Qh, nq4, ntot4);

    dim3 gridA(N_Q / 128, M_K / 128);   // 32 x 64, natural order
    scores_mfma<<<gridA, 256, 0, stream>>>(Qh, Kh, ign, part);
    combine_kernel<<<N_Q, 64, 0, stream>>>(part, Q, K, pos, logp, out + 1);
    loss_kernel<<<1, 256, 0, stream>>>(logp, out);
}

// Round 11
// 97.868 us; speedup vs baseline: 10.3564x; 1.2455x over previous
//
#include <hip/hip_runtime.h>
#include <math.h>

// Problem constants (from reference)
#define N_Q 4096
#define M_K 8192
#define D_DIM 512
#define P_IDX 4
#define INV_TEMP 10.0f

#define NCHUNK 256          // 8192 cols / 32-col (interleaved) chunks

typedef __attribute__((ext_vector_type(4))) _Float16 f16x4;
typedef __attribute__((ext_vector_type(8))) _Float16 f16x8;
typedef __attribute__((ext_vector_type(16))) float f32x16;

// ---------------------------------------------------------------------------
// Convert fp32 -> fp16 (RN), Q and K fused in one launch.
// Q is pre-scaled by INV_TEMP so the GEMM directly yields scores/TEMP.
// ---------------------------------------------------------------------------
__global__ __launch_bounds__(256)
void conv_f16(const float* __restrict__ Q, const float* __restrict__ K,
              _Float16* __restrict__ h, int nq4, int ntot4)
{
    int i = blockIdx.x * 256 + threadIdx.x;
    if (i >= ntot4) return;
    const bool isq = (i < nq4);
    float4 v = isq ? ((const float4*)Q)[i] : ((const float4*)K)[i - nq4];
    const float sc = isq ? INV_TEMP : 1.0f;
    f16x4 o;
    o.x = (_Float16)(v.x * sc); o.y = (_Float16)(v.y * sc);
    o.z = (_Float16)(v.z * sc); o.w = (_Float16)(v.w * sc);
    ((f16x4*)h)[i] = o;
}

__device__ __forceinline__ void gload16(const void* g, const void* l) {
    __builtin_amdgcn_global_load_lds(
        (const __attribute__((address_space(1))) unsigned int*)g,
        (__attribute__((address_space(3))) unsigned int*)l, 16, 0, 0);
}

// ---------------------------------------------------------------------------
// SWAPPED single-pass fp16 MFMA GEMM: computes scores^T via MFMA(K, Q) so
// each lane owns full Q-rows (lane axis = Q-row, reg pattern = K-col).
// 128(K) x 128(Q) tile, BK=32, 4 waves (2x2), 32x32x16_f16, double-buffered
// 2x16 KB staging, one barrier per K-step.  32 KB LDS + <=128 unified regs
// -> 4 blocks/CU (16 waves TLP).  Epilogue: pure in-lane {mask,max,argmax,
// sumexp} over acc regs -- no shuffles -- one float4 partial per lane per
// j-row.  Grid (64 kTiles, 32 qTiles) natural order, block 256.
// ---------------------------------------------------------------------------
__global__ __launch_bounds__(256, 4)
void scores_mfma(const _Float16* __restrict__ Qh, const _Float16* __restrict__ Kh,
                 const int* __restrict__ ign, float4* __restrict__ part)
{
    // buffer layout: [oct(k/8, 0..3)][row(128)][8 f16]; plane0=K, plane1=Q.
    __shared__ __align__(16) _Float16 smem[2][2 * 4096];

    const int tid = threadIdx.x;          // 0..255
    const int lane = tid & 63;
    const int wave = tid >> 6;            // 0..3
    const int wr = wave >> 1, wc = wave & 1;
    const int hi = lane >> 5, lx = lane & 31;
    const int bx = blockIdx.x;            // K-tile index (64)
    const int by = blockIdx.y;            // Q-tile index (32)
    const int krow0 = bx * 128;
    const int qrow0 = by * 128;

    // 4 staging streams per thread: 2 chunks per plane (512 chunks/plane)
    const _Float16* srcs[4];
    int dsts[4];
#pragma unroll
    for (int it = 0; it < 4; ++it) {
        const int plane = it >> 1;
        const int c = (it & 1) * 256 + tid;       // chunk 0..511 within plane
        const int oct = c >> 7, r = c & 127;
        const _Float16* base = (plane == 0) ? Kh : Qh;
        const int grow = ((plane == 0) ? krow0 : qrow0) + r;
        srcs[it] = base + (size_t)grow * D_DIM + oct * 8;
        dsts[it] = plane * 4096 + c * 8;
    }

    f32x16 acc[2][2];
#pragma unroll
    for (int i = 0; i < 2; ++i)
#pragma unroll
        for (int j = 0; j < 2; ++j) acc[i][j] = (f32x16)0.f;

    // prologue: stage K-tile 0 into buffer 0
#pragma unroll
    for (int it = 0; it < 4; ++it)
        gload16(srcs[it], &smem[0][dsts[it]]);
    __syncthreads();        // buf0 fully staged (drains vmcnt, all waves)

    for (int t = 0; t < 16; ++t) {
        const int cur = t & 1;
        // prefetch tile t+1 first -> L2 latency hides under this iteration
        if (t < 15) {
            const int k0 = (t + 1) * 32;
#pragma unroll
            for (int it = 0; it < 4; ++it)
                gload16(srcs[it] + k0, &smem[cur ^ 1][dsts[it]]);
        }

        const _Float16* sbuf = smem[cur];
        f16x8 a[2][2], b[2][2];
#pragma unroll
        for (int ks = 0; ks < 2; ++ks) {
            const int oct = ks * 2 + hi;
#pragma unroll
            for (int i = 0; i < 2; ++i) {
                const int oa = (oct * 128 + wr * 64 + i * 32 + lx) * 8;
                a[i][ks] = *(const f16x8*)&sbuf[oa];               // K plane
            }
#pragma unroll
            for (int j = 0; j < 2; ++j) {
                const int ob = (oct * 128 + wc * 64 + j * 32 + lx) * 8;
                b[j][ks] = *(const f16x8*)&sbuf[4096 + ob];        // Q plane
            }
        }
#pragma unroll
        for (int ks = 0; ks < 2; ++ks)
#pragma unroll
            for (int i = 0; i < 2; ++i)
#pragma unroll
                for (int j = 0; j < 2; ++j)
                    acc[i][j] = __builtin_amdgcn_mfma_f32_32x32x16_f16(a[i][ks], b[j][ks], acc[i][j], 0, 0, 0);

        __syncthreads();    // buf[cur] free + buf[cur^1] staged
    }

    // Epilogue (all in-lane):
    //   acc[i][j][r] = score(qrow = qrow0 + wc*64 + j*32 + lx,
    //                        kcol = krow0 + wr*64 + i*32 + (r&3)+8*(r>>2)+4*hi)
    //   Each lane: 2 Q-rows x 32 K-cols -> chunk partial per (j).
    const int kbase = krow0 + wr * 64 + 4 * hi;
    const int chunk = bx * 4 + wr * 2 + hi;
#pragma unroll
    for (int j = 0; j < 2; ++j) {
        const int qrow = qrow0 + wc * 64 + j * 32 + lx;
        const int4 ig = ((const int4*)ign)[qrow];   // 4 ignore indices, 16B
        float bm = -INFINITY; int bi = 0x7fffffff;
        // pass 1: mask -> write back into acc; running max/argmax
#pragma unroll
        for (int i = 0; i < 2; ++i) {
#pragma unroll
            for (int r = 0; r < 16; ++r) {
                const int col = kbase + i * 32 + (r & 3) + 8 * (r >> 2);
                float x = acc[i][j][r];
                if (col == ig.x || col == ig.y || col == ig.z || col == ig.w)
                    x = -INFINITY;
                acc[i][j][r] = x;
                if (x > bm || (x == bm && col < bi)) { bm = x; bi = col; }
            }
        }
        // pass 2: sumexp
        float se = 0.f;
#pragma unroll
        for (int i = 0; i < 2; ++i)
#pragma unroll
            for (int r = 0; r < 16; ++r)
                se += __expf(acc[i][j][r] - bm);
        part[(size_t)qrow * NCHUNK + chunk] =
            make_float4(bm, se, __int_as_float(bi), 0.f);
    }
}

// ---------------------------------------------------------------------------
// Kernel B: one wave per row.  Merge 256 chunk partials -> lse + argmax;
// positives recomputed EXACTLY in fp32 (with duplicate dedup).
// ---------------------------------------------------------------------------
__global__ __launch_bounds__(64)
void combine_kernel(const float4* __restrict__ part,
                    const float* __restrict__ Q, const float* __restrict__ K,
                    const int* __restrict__ pos,
                    float* __restrict__ logp, float* __restrict__ corrects)
{
    const int row = blockIdx.x;
    const int lane = threadIdx.x;

    float4 p0 = part[(size_t)row * NCHUNK + lane];
    float m = p0.x, s = p0.y, av = p0.x;
    int ai = __float_as_int(p0.z);
#pragma unroll
    for (int k = 1; k < 4; ++k) {
        float4 p = part[(size_t)row * NCHUNK + k * 64 + lane];
        int oi = __float_as_int(p.z);
        float nm = fmaxf(m, p.x);
        s = s * expf(m - nm) + p.y * expf(p.x - nm);
        m = nm;
        if (p.x > av || (p.x == av && oi < ai)) { av = p.x; ai = oi; }
    }

#pragma unroll
    for (int off = 32; off >= 1; off >>= 1) {
        float om = __shfl_xor(m, off);
        float os = __shfl_xor(s, off);
        float oav = __shfl_xor(av, off);
        int oi = __shfl_xor(ai, off);
        float nm = fmaxf(m, om);
        s = s * expf(m - nm) + os * expf(om - nm);
        m = nm;
        if (oav > av || (oav == av && oi < ai)) { av = oav; ai = oi; }
    }
    float lse = m + logf(s);

    int pi[4];
#pragma unroll
    for (int p = 0; p < 4; ++p) pi[p] = pos[row * P_IDX + p];

    // positive dot-products in exact fp32: lane covers 8 consecutive d-elements
    const float4* q4 = (const float4*)(Q + (size_t)row * D_DIM);
    float4 qa = q4[lane * 2], qb = q4[lane * 2 + 1];
    float d[4];
#pragma unroll
    for (int p = 0; p < 4; ++p) {
        const float4* k4 = (const float4*)(K + (size_t)pi[p] * D_DIM);
        float4 ka = k4[lane * 2], kb = k4[lane * 2 + 1];
        d[p] = qa.x * ka.x + qa.y * ka.y + qa.z * ka.z + qa.w * ka.w
             + qb.x * kb.x + qb.y * kb.y + qb.z * kb.z + qb.w * kb.w;
    }
#pragma unroll
    for (int off = 32; off >= 1; off >>= 1) {
#pragma unroll
        for (int p = 0; p < 4; ++p) d[p] += __shfl_xor(d[p], off);
    }

    if (lane == 0) {
        float ps[4];
#pragma unroll
        for (int p = 0; p < 4; ++p) ps[p] = d[p] * INV_TEMP;
        const bool v1 = (pi[1] != pi[0]);
        const bool v2 = (pi[2] != pi[0]) && (pi[2] != pi[1]);
        const bool v3 = (pi[3] != pi[0]) && (pi[3] != pi[1]) && (pi[3] != pi[2]);
        float pm = ps[0];
        if (v1) pm = fmaxf(pm, ps[1]);
        if (v2) pm = fmaxf(pm, ps[2]);
        if (v3) pm = fmaxf(pm, ps[3]);
        float pse = expf(ps[0] - pm);
        if (v1) pse += expf(ps[1] - pm);
        if (v2) pse += expf(ps[2] - pm);
        if (v3) pse += expf(ps[3] - pm);
        float pos_lse = pm + logf(pse);
        logp[row] = pos_lse - lse;
        bool corr = (ai == pi[0]) || (ai == pi[1]) || (ai == pi[2]) || (ai == pi[3]);
        corrects[row] = corr ? 1.0f : 0.0f;
    }
}

// ---------------------------------------------------------------------------
// Kernel C: deterministic fixed-order reduction of logp -> loss
// ---------------------------------------------------------------------------
__global__ __launch_bounds__(256)
void loss_kernel(const float* __restrict__ logp, float* __restrict__ out)
{
    __shared__ float sm[256];
    const int t = threadIdx.x;
    float s = 0.f;
    for (int i = t; i < N_Q; i += 256) s += logp[i];
    sm[t] = s;
    __syncthreads();
    for (int off = 128; off >= 1; off >>= 1) {
        if (t < off) sm[t] += sm[t + off];
        __syncthreads();
    }
    if (t == 0) out[0] = -sm[0];
}

// ---------------------------------------------------------------------------
extern "C" void kernel_launch(void* const* d_in, const int* in_sizes, int n_in,
                              void* d_out, int out_size, void* d_ws, size_t ws_size,
                              hipStream_t stream)
{
    const float* Q = (const float*)d_in[0];
    const float* K = (const float*)d_in[1];
    const int* pos = (const int*)d_in[2];
    const int* ign = (const int*)d_in[3];
    float* out = (float*)d_out;

    // workspace layout (total ~28 MB)
    _Float16* Qh = (_Float16*)d_ws;                              // 4 MB
    _Float16* Kh = Qh + (size_t)N_Q * D_DIM;                     // 8 MB
    float4* part = (float4*)(Kh + (size_t)M_K * D_DIM);          // 16 MB
    float* logp = (float*)(part + (size_t)N_Q * NCHUNK);         // 16 KB

    const int nq4 = N_Q * D_DIM / 4;
    const int ntot4 = (N_Q + M_K) * D_DIM / 4;
    conv_f16<<<(ntot4 + 255) / 256, 256, 0, stream>>>(Q, K, Qh, nq4, ntot4);

    dim3 gridA(M_K / 128, N_Q / 128);   // 64 kTiles x 32 qTiles
    scores_mfma<<<gridA, 256, 0, stream>>>(Qh, Kh, ign, part);
    combine_kernel<<<N_Q, 64, 0, stream>>>(part, Q, K, pos, logp, out + 1);
    loss_kernel<<<1, 256, 0, stream>>>(logp, out);
}